// Round 1
// baseline (9590.157 us; speedup 1.0000x reference)
//
#include <hip/hip_runtime.h>
#include <hip/hip_cooperative_groups.h>

// Problem: B=128, S=256, V=50000, E=512, H=1024, O=10
// Pipeline: cast/gather -> GEMM1 (input projections, fp16 MFMA) -> cooperative
// LSTM scan (fp16 MFMA, fp32 state) -> fp32 FC.
// Workspace budget ~316 MB (gx fp16 is 268 MB).

typedef __attribute__((ext_vector_type(8))) _Float16 half8;
typedef __attribute__((ext_vector_type(4))) float f32x4;

#define MFMA16(a, b, c) __builtin_amdgcn_mfma_f32_16x16x32_f16((a), (b), (c), 0, 0, 0)

__device__ __forceinline__ float sigm(float x) { return 1.0f / (1.0f + __expf(-x)); }
__device__ __forceinline__ float tanh_(float x) { return 1.0f - 2.0f / (__expf(2.0f * x) + 1.0f); }

// ---------------- cast / gather kernels ----------------

// e_f16[m][k] = fp16(emb[x[m]][k]), m = b*256+s, 16M elems, 8/thread
__global__ __launch_bounds__(256) void k_cast_e(const int* __restrict__ x,
                                                const float* __restrict__ emb,
                                                _Float16* __restrict__ e) {
  int idx = (blockIdx.x * 256 + threadIdx.x) * 8;  // < 16777216
  int m = idx >> 9, k = idx & 511;
  int tok = x[m];
  const float* src = emb + (long)tok * 512 + k;
  float4 a = *(const float4*)src;
  float4 b = *(const float4*)(src + 4);
  half8 h;
  h[0] = (_Float16)a.x; h[1] = (_Float16)a.y; h[2] = (_Float16)a.z; h[3] = (_Float16)a.w;
  h[4] = (_Float16)b.x; h[5] = (_Float16)b.y; h[6] = (_Float16)b.z; h[7] = (_Float16)b.w;
  *(half8*)(e + idx) = h;
}

// Wi_f16[n][k], n = g*1024+h, k<512 (concat of the 4 input-weight mats)
__global__ __launch_bounds__(256) void k_cast_wi(const float* __restrict__ Wii, const float* __restrict__ Wif,
                                                 const float* __restrict__ Wig, const float* __restrict__ Wio,
                                                 _Float16* __restrict__ Wi) {
  int idx = (blockIdx.x * 256 + threadIdx.x) * 8;  // < 2097152
  int g = idx >> 19;                               // 524288 elems per gate
  const float* src = (g == 0) ? Wii : (g == 1) ? Wif : (g == 2) ? Wig : Wio;
  src += idx & 524287;
  float4 a = *(const float4*)src;
  float4 b = *(const float4*)(src + 4);
  half8 h;
  h[0] = (_Float16)a.x; h[1] = (_Float16)a.y; h[2] = (_Float16)a.z; h[3] = (_Float16)a.w;
  h[4] = (_Float16)b.x; h[5] = (_Float16)b.y; h[6] = (_Float16)b.z; h[7] = (_Float16)b.w;
  *(half8*)(Wi + idx) = h;
}

// Wh_f16[n'][k], n' = cg*64 + g*16 + cc  (h-col = cg*16+cc), k<1024
__global__ __launch_bounds__(256) void k_cast_wh(const float* __restrict__ Whi, const float* __restrict__ Whf,
                                                 const float* __restrict__ Whg, const float* __restrict__ Who,
                                                 _Float16* __restrict__ Wh) {
  int idx = (blockIdx.x * 256 + threadIdx.x) * 8;  // < 4194304
  int n = idx >> 10, k = idx & 1023;
  int cg = n >> 6, rem = n & 63, g = rem >> 4, cc = rem & 15;
  const float* src = (g == 0) ? Whi : (g == 1) ? Whf : (g == 2) ? Whg : Who;
  src += (cg * 16 + cc) * 1024 + k;
  float4 a = *(const float4*)src;
  float4 b = *(const float4*)(src + 4);
  half8 h;
  h[0] = (_Float16)a.x; h[1] = (_Float16)a.y; h[2] = (_Float16)a.z; h[3] = (_Float16)a.w;
  h[4] = (_Float16)b.x; h[5] = (_Float16)b.y; h[6] = (_Float16)b.z; h[7] = (_Float16)b.w;
  *(half8*)(Wh + idx) = h;
}

// bias_cat[n] fp32, n = g*1024+h
__global__ __launch_bounds__(256) void k_cast_bias(const float* __restrict__ bii, const float* __restrict__ bif,
                                                   const float* __restrict__ big, const float* __restrict__ bio,
                                                   float* __restrict__ bc) {
  int n = blockIdx.x * 256 + threadIdx.x;  // < 4096
  int g = n >> 10, hh = n & 1023;
  const float* src = (g == 0) ? bii : (g == 1) ? bif : (g == 2) ? big : bio;
  bc[n] = src[hh];
}

// ---------------- GEMM1: gx[s][g][b][h] = e @ Wi^T + bias ----------------
// M=32768 (m=b*256+s), N=4096 (n=g*1024+h), K=512. 128x128 tile, BK=32.
__global__ __launch_bounds__(256) void k_gemm1(const _Float16* __restrict__ E, const _Float16* __restrict__ Wi,
                                               const float* __restrict__ bias, _Float16* __restrict__ gx) {
  __shared__ _Float16 As[128][40];  // +8 pad: 2-way banks (free)
  __shared__ _Float16 Bs[128][40];
  const int t = threadIdx.x;
  const int bm = blockIdx.x >> 5, bn = blockIdx.x & 31;
  const int m0 = bm << 7, n0 = bn << 7;
  const int lane = t & 63, wv = t >> 6;
  const int wm = (wv >> 1) << 6, wn = (wv & 1) << 6;
  const int ln = lane & 15, q = lane >> 4;
  const int rowA0 = t >> 2, kc0 = t & 3;
  const int rowA1 = (t + 256) >> 2, kc1 = (t + 256) & 3;

  f32x4 acc[4][4] = {};

  for (int k0 = 0; k0 < 512; k0 += 32) {
    *(half8*)&As[rowA0][kc0 * 8] = *(const half8*)(E + (m0 + rowA0) * 512 + k0 + kc0 * 8);
    *(half8*)&As[rowA1][kc1 * 8] = *(const half8*)(E + (m0 + rowA1) * 512 + k0 + kc1 * 8);
    *(half8*)&Bs[rowA0][kc0 * 8] = *(const half8*)(Wi + (n0 + rowA0) * 512 + k0 + kc0 * 8);
    *(half8*)&Bs[rowA1][kc1 * 8] = *(const half8*)(Wi + (n0 + rowA1) * 512 + k0 + kc1 * 8);
    __syncthreads();
    half8 af[4], bf[4];
#pragma unroll
    for (int i = 0; i < 4; i++) af[i] = *(const half8*)&As[wm + i * 16 + ln][q * 8];
#pragma unroll
    for (int i = 0; i < 4; i++) bf[i] = *(const half8*)&Bs[wn + i * 16 + ln][q * 8];
#pragma unroll
    for (int mi = 0; mi < 4; mi++)
#pragma unroll
      for (int ni = 0; ni < 4; ni++) acc[mi][ni] = MFMA16(af[mi], bf[ni], acc[mi][ni]);
    __syncthreads();
  }

#pragma unroll
  for (int ni = 0; ni < 4; ni++) {
    int n = n0 + wn + ni * 16 + ln;
    float bv = bias[n];
    int g = n >> 10, hh = n & 1023;
#pragma unroll
    for (int mi = 0; mi < 4; mi++) {
#pragma unroll
      for (int r = 0; r < 4; r++) {
        int m = m0 + wm + mi * 16 + q * 4 + r;
        int b = m >> 8, s = m & 255;
        float v = acc[mi][ni][r] + bv;
        gx[(long)(((s << 2) | g) * 128 + b) * 1024 + hh] = (_Float16)v;
      }
    }
  }
}

// ---------------- cooperative LSTM scan ----------------
// 256 WGs = 64 col-groups x 4 row-splits; WG owns rows [r0,r0+32) x h-cols [c0,c0+16).
// wave w = gate w; W_h fragments pinned in VGPRs; c-state in regs; h fp16 ping-pong in global.
__global__ __launch_bounds__(256, 1) void k_lstm(const _Float16* __restrict__ gx, const _Float16* __restrict__ Wh,
                                                 _Float16* __restrict__ hbuf, float* __restrict__ hT) {
  __shared__ float pre[4][32][17];
  const int bid = blockIdx.x;
  const int cg = bid & 63, rs = bid >> 6;
  const int r0 = rs << 5, c0 = cg << 4;
  const int t = threadIdx.x, lane = t & 63, w = t >> 6;
  const int ln = lane & 15, q = lane >> 4;

  // pin this wave's W_h B-fragments in registers: rows cg*64 + w*16 + ln, all K
  half8 breg[32];
  const _Float16* wrow = Wh + (cg * 64 + w * 16 + ln) * 1024 + q * 8;
#pragma unroll
  for (int ks = 0; ks < 32; ks++) breg[ks] = *(const half8*)(wrow + ks * 32);

  // zero our slice of h buffer 0
  const int e0 = t << 1;
  const int erow = e0 >> 4, ecol = e0 & 15;
  *(unsigned int*)(hbuf + (r0 + erow) * 1024 + c0 + ecol) = 0u;

  float cst0 = 0.f, cst1 = 0.f;
  auto grid = cooperative_groups::this_grid();
  grid.sync();

  // prefetch gx for s=0
  float nx[2][4];
  {
    const _Float16* gp = gx + (long)((0 * 4 + w) * 128 + r0) * 1024 + c0 + ln;
#pragma unroll
    for (int mi = 0; mi < 2; mi++)
#pragma unroll
      for (int r = 0; r < 4; r++) nx[mi][r] = (float)gp[(mi * 16 + q * 4 + r) * 1024];
  }

  for (int s = 0; s < 256; s++) {
    const _Float16* hcur = hbuf + (s & 1) * 131072;
    _Float16* hnxt = hbuf + ((s + 1) & 1) * 131072;

    f32x4 acc0, acc1;
#pragma unroll
    for (int r = 0; r < 4; r++) { acc0[r] = nx[0][r]; acc1[r] = nx[1][r]; }

    // prefetch next step's gx (hidden under this step's K-loop)
    {
      int sp = (s < 255) ? s + 1 : 255;
      const _Float16* gp = gx + (long)((sp * 4 + w) * 128 + r0) * 1024 + c0 + ln;
#pragma unroll
      for (int mi = 0; mi < 2; mi++)
#pragma unroll
        for (int r = 0; r < 4; r++) nx[mi][r] = (float)gp[(mi * 16 + q * 4 + r) * 1024];
    }

    const _Float16* arow0 = hcur + (r0 + ln) * 1024 + q * 8;
    const _Float16* arow1 = arow0 + 16 * 1024;
#pragma unroll
    for (int ks = 0; ks < 32; ks++) {
      half8 a0 = *(const half8*)(arow0 + ks * 32);
      half8 a1 = *(const half8*)(arow1 + ks * 32);
      acc0 = MFMA16(a0, breg[ks], acc0);
      acc1 = MFMA16(a1, breg[ks], acc1);
    }

#pragma unroll
    for (int r = 0; r < 4; r++) {
      pre[w][q * 4 + r][ln] = acc0[r];
      pre[w][16 + q * 4 + r][ln] = acc1[r];
    }
    __syncthreads();

    float xi0 = pre[0][erow][ecol], xf0 = pre[1][erow][ecol];
    float xg0 = pre[2][erow][ecol], xo0 = pre[3][erow][ecol];
    float xi1 = pre[0][erow][ecol + 1], xf1 = pre[1][erow][ecol + 1];
    float xg1 = pre[2][erow][ecol + 1], xo1 = pre[3][erow][ecol + 1];
    float i0 = sigm(xi0), f0 = sigm(xf0), g0 = tanh_(xg0), o0 = sigm(xo0);
    float i1 = sigm(xi1), f1 = sigm(xf1), g1 = tanh_(xg1), o1 = sigm(xo1);
    cst0 = f0 * cst0 + i0 * g0;
    cst1 = f1 * cst1 + i1 * g1;
    float h0 = o0 * tanh_(cst0);
    float h1 = o1 * tanh_(cst1);
    union { _Float16 h[2]; unsigned int u; } pk;
    pk.h[0] = (_Float16)h0; pk.h[1] = (_Float16)h1;
    *(unsigned int*)(hnxt + (r0 + erow) * 1024 + c0 + ecol) = pk.u;
    if (s == 255) {
      float* hp = hT + (r0 + erow) * 1024 + c0 + ecol;
      hp[0] = h0; hp[1] = h1;
    }
    grid.sync();
  }
}

// ---------------- final FC (exact fp32): out[b][o] = hT[b] . fcW[o] + fcb[o] ----------------
__global__ __launch_bounds__(256) void k_fc(const float* __restrict__ hT, const float* __restrict__ W,
                                            const float* __restrict__ bias, float* __restrict__ out) {
  int gid = blockIdx.x * 4 + (threadIdx.x >> 6);  // wave id < 1280
  int lane = threadIdx.x & 63;
  int b = gid / 10, o = gid - b * 10;
  const float* hp = hT + b * 1024;
  const float* wp = W + o * 1024;
  float sum = 0.f;
  for (int k = lane; k < 1024; k += 64) sum += hp[k] * wp[k];
#pragma unroll
  for (int off = 32; off > 0; off >>= 1) sum += __shfl_down(sum, off, 64);
  if (lane == 0) out[b * 10 + o] = sum + bias[o];
}

// ---------------- launch ----------------
extern "C" void kernel_launch(void* const* d_in, const int* in_sizes, int n_in,
                              void* d_out, int out_size, void* d_ws, size_t ws_size,
                              hipStream_t stream) {
  const int* x = (const int*)d_in[0];
  const float* emb = (const float*)d_in[1];
  const float* Wii = (const float*)d_in[2];
  const float* bii = (const float*)d_in[3];
  const float* Whi = (const float*)d_in[4];
  const float* Wif = (const float*)d_in[5];
  const float* bif = (const float*)d_in[6];
  const float* Whf = (const float*)d_in[7];
  const float* Wig = (const float*)d_in[8];
  const float* big = (const float*)d_in[9];
  const float* Whg = (const float*)d_in[10];
  const float* Wio = (const float*)d_in[11];
  const float* bio = (const float*)d_in[12];
  const float* Who = (const float*)d_in[13];
  const float* fcW = (const float*)d_in[14];
  const float* fcb = (const float*)d_in[15];

  char* ws = (char*)d_ws;
  _Float16* gx = (_Float16*)ws;                    // 268,435,456 B
  _Float16* E = (_Float16*)(ws + 268435456);       // 33,554,432 B
  _Float16* WiB = (_Float16*)(ws + 301989888);     // 4,194,304 B
  _Float16* WhB = (_Float16*)(ws + 306184192);     // 8,388,608 B
  float* biasC = (float*)(ws + 314572800);         // 16,384 B
  _Float16* hbuf = (_Float16*)(ws + 314589184);    // 524,288 B
  float* hT = (float*)(ws + 315113472);            // 524,288 B (total ~316 MB)
  float* out = (float*)d_out;

  k_cast_e<<<8192, 256, 0, stream>>>(x, emb, E);
  k_cast_wi<<<1024, 256, 0, stream>>>(Wii, Wif, Wig, Wio, WiB);
  k_cast_wh<<<2048, 256, 0, stream>>>(Whi, Whf, Whg, Who, WhB);
  k_cast_bias<<<16, 256, 0, stream>>>(bii, bif, big, bio, biasC);
  k_gemm1<<<8192, 256, 0, stream>>>(E, WiB, biasC, gx);

  const _Float16* gx_a = gx;
  const _Float16* wh_a = WhB;
  _Float16* hb_a = hbuf;
  float* ht_a = hT;
  void* kargs[] = {(void*)&gx_a, (void*)&wh_a, (void*)&hb_a, (void*)&ht_a};
  hipLaunchCooperativeKernel(k_lstm, dim3(256), dim3(256), kargs, 0, stream);

  k_fc<<<320, 256, 0, stream>>>(hT, fcW, fcb, out);
}

// Round 2
// 6258.401 us; speedup vs baseline: 1.5324x; 1.5324x over previous
//
#include <hip/hip_runtime.h>
#include <hip/hip_cooperative_groups.h>

// Problem: B=128, S=256, V=50000, E=512, H=1024, O=10
// Pipeline: cast/gather -> GEMM1 (input projections, fp16 MFMA, tiled gx output)
// -> cooperative LSTM scan with PER-BATCH-GROUP custom barriers (4 groups x 64 WGs;
//    batch rows are independent, so no grid-wide sync needed) -> fp32 FC.

typedef __attribute__((ext_vector_type(8))) _Float16 half8;
typedef __attribute__((ext_vector_type(4))) float f32x4;

#define MFMA16(a, b, c) __builtin_amdgcn_mfma_f32_16x16x32_f16((a), (b), (c), 0, 0, 0)

__device__ __forceinline__ float sigm(float x) { return 1.0f / (1.0f + __expf(-x)); }
__device__ __forceinline__ float tanh_(float x) { return 1.0f - 2.0f / (__expf(2.0f * x) + 1.0f); }

// ---------------- cast / gather kernels ----------------

__global__ __launch_bounds__(256) void k_cast_e(const int* __restrict__ x,
                                                const float* __restrict__ emb,
                                                _Float16* __restrict__ e) {
  int idx = (blockIdx.x * 256 + threadIdx.x) * 8;  // < 16777216
  int m = idx >> 9, k = idx & 511;
  int tok = x[m];
  const float* src = emb + (long)tok * 512 + k;
  float4 a = *(const float4*)src;
  float4 b = *(const float4*)(src + 4);
  half8 h;
  h[0] = (_Float16)a.x; h[1] = (_Float16)a.y; h[2] = (_Float16)a.z; h[3] = (_Float16)a.w;
  h[4] = (_Float16)b.x; h[5] = (_Float16)b.y; h[6] = (_Float16)b.z; h[7] = (_Float16)b.w;
  *(half8*)(e + idx) = h;
}

__global__ __launch_bounds__(256) void k_cast_wi(const float* __restrict__ Wii, const float* __restrict__ Wif,
                                                 const float* __restrict__ Wig, const float* __restrict__ Wio,
                                                 _Float16* __restrict__ Wi) {
  int idx = (blockIdx.x * 256 + threadIdx.x) * 8;  // < 2097152
  int g = idx >> 19;
  const float* src = (g == 0) ? Wii : (g == 1) ? Wif : (g == 2) ? Wig : Wio;
  src += idx & 524287;
  float4 a = *(const float4*)src;
  float4 b = *(const float4*)(src + 4);
  half8 h;
  h[0] = (_Float16)a.x; h[1] = (_Float16)a.y; h[2] = (_Float16)a.z; h[3] = (_Float16)a.w;
  h[4] = (_Float16)b.x; h[5] = (_Float16)b.y; h[6] = (_Float16)b.z; h[7] = (_Float16)b.w;
  *(half8*)(Wi + idx) = h;
}

// Wh_f16[n'][k], n' = cg*64 + g*16 + cc  (h-col = cg*16+cc), k<1024
__global__ __launch_bounds__(256) void k_cast_wh(const float* __restrict__ Whi, const float* __restrict__ Whf,
                                                 const float* __restrict__ Whg, const float* __restrict__ Who,
                                                 _Float16* __restrict__ Wh) {
  int idx = (blockIdx.x * 256 + threadIdx.x) * 8;  // < 4194304
  int n = idx >> 10, k = idx & 1023;
  int cg = n >> 6, rem = n & 63, g = rem >> 4, cc = rem & 15;
  const float* src = (g == 0) ? Whi : (g == 1) ? Whf : (g == 2) ? Whg : Who;
  src += (cg * 16 + cc) * 1024 + k;
  float4 a = *(const float4*)src;
  float4 b = *(const float4*)(src + 4);
  half8 h;
  h[0] = (_Float16)a.x; h[1] = (_Float16)a.y; h[2] = (_Float16)a.z; h[3] = (_Float16)a.w;
  h[4] = (_Float16)b.x; h[5] = (_Float16)b.y; h[6] = (_Float16)b.z; h[7] = (_Float16)b.w;
  *(half8*)(Wh + idx) = h;
}

__global__ __launch_bounds__(256) void k_cast_bias(const float* __restrict__ bii, const float* __restrict__ bif,
                                                   const float* __restrict__ big, const float* __restrict__ bio,
                                                   float* __restrict__ bc) {
  int n = blockIdx.x * 256 + threadIdx.x;  // < 4096
  int g = n >> 10, hh = n & 1023;
  const float* src = (g == 0) ? bii : (g == 1) ? bif : (g == 2) ? big : bio;
  bc[n] = src[hh];
}

__global__ void k_zero(unsigned int* p) { p[threadIdx.x] = 0u; }

// ---------------- GEMM1: tiled gx output ----------------
// gx tile layout: tile(s, rs, cg, g)[row=b&31][col=h&15], tile = 512 fp16 contiguous.
// offset = (((s*4+rs)*64+cg)*4+g)*512 + b32*16 + col
__global__ __launch_bounds__(256) void k_gemm1(const _Float16* __restrict__ E, const _Float16* __restrict__ Wi,
                                               const float* __restrict__ bias, _Float16* __restrict__ gx) {
  __shared__ _Float16 As[128][40];
  __shared__ _Float16 Bs[128][40];
  const int t = threadIdx.x;
  const int bm = blockIdx.x >> 5, bn = blockIdx.x & 31;
  const int m0 = bm << 7, n0 = bn << 7;
  const int lane = t & 63, wv = t >> 6;
  const int wm = (wv >> 1) << 6, wn = (wv & 1) << 6;
  const int ln = lane & 15, q = lane >> 4;
  const int rowA0 = t >> 2, kc0 = t & 3;
  const int rowA1 = (t + 256) >> 2, kc1 = (t + 256) & 3;

  f32x4 acc[4][4] = {};

  for (int k0 = 0; k0 < 512; k0 += 32) {
    *(half8*)&As[rowA0][kc0 * 8] = *(const half8*)(E + (m0 + rowA0) * 512 + k0 + kc0 * 8);
    *(half8*)&As[rowA1][kc1 * 8] = *(const half8*)(E + (m0 + rowA1) * 512 + k0 + kc1 * 8);
    *(half8*)&Bs[rowA0][kc0 * 8] = *(const half8*)(Wi + (n0 + rowA0) * 512 + k0 + kc0 * 8);
    *(half8*)&Bs[rowA1][kc1 * 8] = *(const half8*)(Wi + (n0 + rowA1) * 512 + k0 + kc1 * 8);
    __syncthreads();
    half8 af[4], bf[4];
#pragma unroll
    for (int i = 0; i < 4; i++) af[i] = *(const half8*)&As[wm + i * 16 + ln][q * 8];
#pragma unroll
    for (int i = 0; i < 4; i++) bf[i] = *(const half8*)&Bs[wn + i * 16 + ln][q * 8];
#pragma unroll
    for (int mi = 0; mi < 4; mi++)
#pragma unroll
      for (int ni = 0; ni < 4; ni++) acc[mi][ni] = MFMA16(af[mi], bf[ni], acc[mi][ni]);
    __syncthreads();
  }

#pragma unroll
  for (int ni = 0; ni < 4; ni++) {
    int n = n0 + wn + ni * 16 + ln;
    float bv = bias[n];
    int g = n >> 10, hh = n & 1023;
    int cg = hh >> 4, col = hh & 15;
#pragma unroll
    for (int mi = 0; mi < 4; mi++) {
#pragma unroll
      for (int r = 0; r < 4; r++) {
        int m = m0 + wm + mi * 16 + q * 4 + r;
        int b = m >> 8, s = m & 255;
        int rs = b >> 5, b32 = b & 31;
        float v = acc[mi][ni][r] + bv;
        long off = ((long)(((s * 4 + rs) * 64 + cg) * 4 + g)) * 512 + b32 * 16 + col;
        gx[off] = (_Float16)v;
      }
    }
  }
}

// ---------------- custom per-group barrier ----------------
__device__ __forceinline__ void gbar(unsigned int* cnt, unsigned int target) {
  __syncthreads();  // all waves drain their vmem (h stores) before arrival
  if (threadIdx.x == 0) {
    __builtin_amdgcn_fence(__ATOMIC_RELEASE, "agent");
    __hip_atomic_fetch_add(cnt, 1u, __ATOMIC_RELAXED, __HIP_MEMORY_SCOPE_AGENT);
    while (__hip_atomic_load(cnt, __ATOMIC_RELAXED, __HIP_MEMORY_SCOPE_AGENT) < target)
      __builtin_amdgcn_s_sleep(2);
  }
  __syncthreads();
  __builtin_amdgcn_fence(__ATOMIC_ACQUIRE, "agent");
}

// ---------------- LSTM scan: 4 batch groups x 64 WGs, per-group barriers ----------------
// WG (rs,cg) owns batch rows [32rs,32rs+32) x h-cols [16cg,16cg+16), all 4 gates (wave=gate).
// W_h fragments pinned in registers; c-state in registers; h fp16 ping-pong in global.
__global__ __launch_bounds__(256, 1) void k_lstm(const _Float16* __restrict__ gx, const _Float16* __restrict__ Wh,
                                                 _Float16* __restrict__ hbuf, float* __restrict__ hT,
                                                 unsigned int* __restrict__ cnt) {
  __shared__ float pre[4][32][17];
  const int bid = blockIdx.x;
  const int cg = bid & 63, rs = bid >> 6;
  const int r0 = rs << 5, c0 = cg << 4;
  const int t = threadIdx.x, lane = t & 63, w = t >> 6;
  const int ln = lane & 15, q = lane >> 4;
  unsigned int* mycnt = cnt + rs * 64;  // 256 B apart per group
  unsigned int tgt = 64;

  // pin this wave's W_h B-fragments: rows cg*64 + w*16 + ln, all K
  half8 breg[32];
  const _Float16* wrow = Wh + (cg * 64 + w * 16 + ln) * 1024 + q * 8;
#pragma unroll
  for (int ks = 0; ks < 32; ks++) breg[ks] = *(const half8*)(wrow + ks * 32);

  const int e0 = t << 1;
  const int erow = e0 >> 4, ecol = e0 & 15;
  *(unsigned int*)(hbuf + (r0 + erow) * 1024 + c0 + ecol) = 0u;

  float cst0 = 0.f, cst1 = 0.f;
  gbar(mycnt, tgt); tgt += 64;

  // prefetch gx tile for s=0 (coalesced u32: gate g at [g*256 + t])
  unsigned int cur[4];
  {
    const unsigned int* gp = (const unsigned int*)gx + (long)((rs * 64 + cg) * 4) * 256;
#pragma unroll
    for (int g = 0; g < 4; g++) cur[g] = gp[g * 256 + t];
  }

  for (int s = 0; s < 256; s++) {
    const _Float16* hcur = hbuf + (s & 1) * 131072;
    _Float16* hnxt = hbuf + ((s + 1) & 1) * 131072;

    // issue next-step gx prefetch (hidden under K-loop)
    unsigned int nx[4];
    {
      int sp = (s < 255) ? s + 1 : 255;
      const unsigned int* gp = (const unsigned int*)gx + (long)(((sp * 4 + rs) * 64 + cg) * 4) * 256;
#pragma unroll
      for (int g = 0; g < 4; g++) nx[g] = gp[g * 256 + t];
    }

    f32x4 acc0 = {}, acc1 = {};
    const _Float16* arow0 = hcur + (r0 + ln) * 1024 + q * 8;
    const _Float16* arow1 = arow0 + 16 * 1024;
#pragma unroll
    for (int ks = 0; ks < 32; ks++) {
      half8 a0 = *(const half8*)(arow0 + ks * 32);
      half8 a1 = *(const half8*)(arow1 + ks * 32);
      acc0 = MFMA16(a0, breg[ks], acc0);
      acc1 = MFMA16(a1, breg[ks], acc1);
    }

#pragma unroll
    for (int r = 0; r < 4; r++) {
      pre[w][q * 4 + r][ln] = acc0[r];
      pre[w][16 + q * 4 + r][ln] = acc1[r];
    }
    __syncthreads();

    union { unsigned int u; _Float16 h[2]; } gi, gf, gg, go;
    gi.u = cur[0]; gf.u = cur[1]; gg.u = cur[2]; go.u = cur[3];
    float xi0 = pre[0][erow][ecol] + (float)gi.h[0];
    float xf0 = pre[1][erow][ecol] + (float)gf.h[0];
    float xg0 = pre[2][erow][ecol] + (float)gg.h[0];
    float xo0 = pre[3][erow][ecol] + (float)go.h[0];
    float xi1 = pre[0][erow][ecol + 1] + (float)gi.h[1];
    float xf1 = pre[1][erow][ecol + 1] + (float)gf.h[1];
    float xg1 = pre[2][erow][ecol + 1] + (float)gg.h[1];
    float xo1 = pre[3][erow][ecol + 1] + (float)go.h[1];
    float i0 = sigm(xi0), f0 = sigm(xf0), g0 = tanh_(xg0), o0 = sigm(xo0);
    float i1 = sigm(xi1), f1 = sigm(xf1), g1 = tanh_(xg1), o1 = sigm(xo1);
    cst0 = f0 * cst0 + i0 * g0;
    cst1 = f1 * cst1 + i1 * g1;
    float h0 = o0 * tanh_(cst0);
    float h1 = o1 * tanh_(cst1);
    union { _Float16 h[2]; unsigned int u; } pk;
    pk.h[0] = (_Float16)h0; pk.h[1] = (_Float16)h1;
    *(unsigned int*)(hnxt + (r0 + erow) * 1024 + c0 + ecol) = pk.u;
    if (s == 255) {
      float* hp = hT + (r0 + erow) * 1024 + c0 + ecol;
      hp[0] = h0; hp[1] = h1;
    } else {
      gbar(mycnt, tgt); tgt += 64;
    }
    cur[0] = nx[0]; cur[1] = nx[1]; cur[2] = nx[2]; cur[3] = nx[3];
  }
}

// ---------------- final FC (exact fp32) ----------------
__global__ __launch_bounds__(256) void k_fc(const float* __restrict__ hT, const float* __restrict__ W,
                                            const float* __restrict__ bias, float* __restrict__ out) {
  int gid = blockIdx.x * 4 + (threadIdx.x >> 6);  // wave id < 1280
  int lane = threadIdx.x & 63;
  int b = gid / 10, o = gid - b * 10;
  const float* hp = hT + b * 1024;
  const float* wp = W + o * 1024;
  float sum = 0.f;
  for (int k = lane; k < 1024; k += 64) sum += hp[k] * wp[k];
#pragma unroll
  for (int off = 32; off > 0; off >>= 1) sum += __shfl_down(sum, off, 64);
  if (lane == 0) out[b * 10 + o] = sum + bias[o];
}

// ---------------- launch ----------------
extern "C" void kernel_launch(void* const* d_in, const int* in_sizes, int n_in,
                              void* d_out, int out_size, void* d_ws, size_t ws_size,
                              hipStream_t stream) {
  const int* x = (const int*)d_in[0];
  const float* emb = (const float*)d_in[1];
  const float* Wii = (const float*)d_in[2];
  const float* bii = (const float*)d_in[3];
  const float* Whi = (const float*)d_in[4];
  const float* Wif = (const float*)d_in[5];
  const float* bif = (const float*)d_in[6];
  const float* Whf = (const float*)d_in[7];
  const float* Wig = (const float*)d_in[8];
  const float* big = (const float*)d_in[9];
  const float* Whg = (const float*)d_in[10];
  const float* Wio = (const float*)d_in[11];
  const float* bio = (const float*)d_in[12];
  const float* Who = (const float*)d_in[13];
  const float* fcW = (const float*)d_in[14];
  const float* fcb = (const float*)d_in[15];

  char* ws = (char*)d_ws;
  _Float16* gx = (_Float16*)ws;                    // 268,435,456 B
  _Float16* E = (_Float16*)(ws + 268435456);       // 33,554,432 B
  _Float16* WiB = (_Float16*)(ws + 301989888);     // 4,194,304 B
  _Float16* WhB = (_Float16*)(ws + 306184192);     // 8,388,608 B
  float* biasC = (float*)(ws + 314572800);         // 16,384 B
  _Float16* hbuf = (_Float16*)(ws + 314589184);    // 524,288 B
  float* hT = (float*)(ws + 315113472);            // 524,288 B
  unsigned int* cnt = (unsigned int*)(ws + 315637760);  // 1,024 B (total ~316 MB)
  float* out = (float*)d_out;

  k_cast_e<<<8192, 256, 0, stream>>>(x, emb, E);
  k_cast_wi<<<1024, 256, 0, stream>>>(Wii, Wif, Wig, Wio, WiB);
  k_cast_wh<<<2048, 256, 0, stream>>>(Whi, Whf, Whg, Who, WhB);
  k_cast_bias<<<16, 256, 0, stream>>>(bii, bif, big, bio, biasC);
  k_gemm1<<<8192, 256, 0, stream>>>(E, WiB, biasC, gx);
  k_zero<<<1, 256, 0, stream>>>(cnt);

  const _Float16* gx_a = gx;
  const _Float16* wh_a = WhB;
  _Float16* hb_a = hbuf;
  float* ht_a = hT;
  unsigned int* cnt_a = cnt;
  void* kargs[] = {(void*)&gx_a, (void*)&wh_a, (void*)&hb_a, (void*)&ht_a, (void*)&cnt_a};
  hipLaunchCooperativeKernel(k_lstm, dim3(256), dim3(256), kargs, 0, stream);

  k_fc<<<320, 256, 0, stream>>>(hT, fcW, fcb, out);
}

// Round 5
// 6127.995 us; speedup vs baseline: 1.5650x; 1.0213x over previous
//
#include <hip/hip_runtime.h>
#include <hip/hip_cooperative_groups.h>

// Problem: B=128, S=256, V=50000, E=512, H=1024, O=10
// R5 = bisection build: EXACT R2 data path (direct global h reads in K-loop,
// plain h stores, untiled gx [s][g][b][h], release/acquire agent fences) with
// ONE change: the per-group barrier is banked (16 arrival lines) + detector WG
// + flag line, replacing the 64-serialized-RMW single line of R2.

typedef __attribute__((ext_vector_type(8))) _Float16 half8;
typedef __attribute__((ext_vector_type(4))) float f32x4;

#define MFMA16(a, b, c) __builtin_amdgcn_mfma_f32_16x16x32_f16((a), (b), (c), 0, 0, 0)

__device__ __forceinline__ float sigm(float x) { return 1.0f / (1.0f + __expf(-x)); }
__device__ __forceinline__ float tanh_(float x) { return 1.0f - 2.0f / (__expf(2.0f * x) + 1.0f); }

// ---------------- cast / gather kernels ----------------

__global__ __launch_bounds__(256) void k_cast_e(const int* __restrict__ x,
                                                const float* __restrict__ emb,
                                                _Float16* __restrict__ e) {
  int idx = (blockIdx.x * 256 + threadIdx.x) * 8;  // < 16777216
  int m = idx >> 9, k = idx & 511;
  int tok = x[m];
  const float* src = emb + (long)tok * 512 + k;
  float4 a = *(const float4*)src;
  float4 b = *(const float4*)(src + 4);
  half8 h;
  h[0] = (_Float16)a.x; h[1] = (_Float16)a.y; h[2] = (_Float16)a.z; h[3] = (_Float16)a.w;
  h[4] = (_Float16)b.x; h[5] = (_Float16)b.y; h[6] = (_Float16)b.z; h[7] = (_Float16)b.w;
  *(half8*)(e + idx) = h;
}

__global__ __launch_bounds__(256) void k_cast_wi(const float* __restrict__ Wii, const float* __restrict__ Wif,
                                                 const float* __restrict__ Wig, const float* __restrict__ Wio,
                                                 _Float16* __restrict__ Wi) {
  int idx = (blockIdx.x * 256 + threadIdx.x) * 8;  // < 2097152
  int g = idx >> 19;
  const float* src = (g == 0) ? Wii : (g == 1) ? Wif : (g == 2) ? Wig : Wio;
  src += idx & 524287;
  float4 a = *(const float4*)src;
  float4 b = *(const float4*)(src + 4);
  half8 h;
  h[0] = (_Float16)a.x; h[1] = (_Float16)a.y; h[2] = (_Float16)a.z; h[3] = (_Float16)a.w;
  h[4] = (_Float16)b.x; h[5] = (_Float16)b.y; h[6] = (_Float16)b.z; h[7] = (_Float16)b.w;
  *(half8*)(Wi + idx) = h;
}

// Wh_f16[n'][k], n' = cg*64 + g*16 + cc  (h-col = cg*16+cc), k<1024
__global__ __launch_bounds__(256) void k_cast_wh(const float* __restrict__ Whi, const float* __restrict__ Whf,
                                                 const float* __restrict__ Whg, const float* __restrict__ Who,
                                                 _Float16* __restrict__ Wh) {
  int idx = (blockIdx.x * 256 + threadIdx.x) * 8;  // < 4194304
  int n = idx >> 10, k = idx & 1023;
  int cg = n >> 6, rem = n & 63, g = rem >> 4, cc = rem & 15;
  const float* src = (g == 0) ? Whi : (g == 1) ? Whf : (g == 2) ? Whg : Who;
  src += (cg * 16 + cc) * 1024 + k;
  float4 a = *(const float4*)src;
  float4 b = *(const float4*)(src + 4);
  half8 h;
  h[0] = (_Float16)a.x; h[1] = (_Float16)a.y; h[2] = (_Float16)a.z; h[3] = (_Float16)a.w;
  h[4] = (_Float16)b.x; h[5] = (_Float16)b.y; h[6] = (_Float16)b.z; h[7] = (_Float16)b.w;
  *(half8*)(Wh + idx) = h;
}

__global__ __launch_bounds__(256) void k_cast_bias(const float* __restrict__ bii, const float* __restrict__ bif,
                                                   const float* __restrict__ big, const float* __restrict__ bio,
                                                   float* __restrict__ bc) {
  int n = blockIdx.x * 256 + threadIdx.x;  // < 4096
  int g = n >> 10, hh = n & 1023;
  const float* src = (g == 0) ? bii : (g == 1) ? bif : (g == 2) ? big : bio;
  bc[n] = src[hh];
}

__global__ void k_zero(unsigned int* p) { p[blockIdx.x * 256 + threadIdx.x] = 0u; }

// ---------------- GEMM1: gx[s][g][b][h] = e @ Wi^T + bias (EXACT R2) ----------------
__global__ __launch_bounds__(256) void k_gemm1(const _Float16* __restrict__ E, const _Float16* __restrict__ Wi,
                                               const float* __restrict__ bias, _Float16* __restrict__ gx) {
  __shared__ _Float16 As[128][40];
  __shared__ _Float16 Bs[128][40];
  const int t = threadIdx.x;
  const int bm = blockIdx.x >> 5, bn = blockIdx.x & 31;
  const int m0 = bm << 7, n0 = bn << 7;
  const int lane = t & 63, wv = t >> 6;
  const int wm = (wv >> 1) << 6, wn = (wv & 1) << 6;
  const int ln = lane & 15, q = lane >> 4;
  const int rowA0 = t >> 2, kc0 = t & 3;
  const int rowA1 = (t + 256) >> 2, kc1 = (t + 256) & 3;

  f32x4 acc[4][4] = {};

  for (int k0 = 0; k0 < 512; k0 += 32) {
    *(half8*)&As[rowA0][kc0 * 8] = *(const half8*)(E + (m0 + rowA0) * 512 + k0 + kc0 * 8);
    *(half8*)&As[rowA1][kc1 * 8] = *(const half8*)(E + (m0 + rowA1) * 512 + k0 + kc1 * 8);
    *(half8*)&Bs[rowA0][kc0 * 8] = *(const half8*)(Wi + (n0 + rowA0) * 512 + k0 + kc0 * 8);
    *(half8*)&Bs[rowA1][kc1 * 8] = *(const half8*)(Wi + (n0 + rowA1) * 512 + k0 + kc1 * 8);
    __syncthreads();
    half8 af[4], bf[4];
#pragma unroll
    for (int i = 0; i < 4; i++) af[i] = *(const half8*)&As[wm + i * 16 + ln][q * 8];
#pragma unroll
    for (int i = 0; i < 4; i++) bf[i] = *(const half8*)&Bs[wn + i * 16 + ln][q * 8];
#pragma unroll
    for (int mi = 0; mi < 4; mi++)
#pragma unroll
      for (int ni = 0; ni < 4; ni++) acc[mi][ni] = MFMA16(af[mi], bf[ni], acc[mi][ni]);
    __syncthreads();
  }

#pragma unroll
  for (int ni = 0; ni < 4; ni++) {
    int n = n0 + wn + ni * 16 + ln;
    float bv = bias[n];
    int g = n >> 10, hh = n & 1023;
#pragma unroll
    for (int mi = 0; mi < 4; mi++) {
#pragma unroll
      for (int r = 0; r < 4; r++) {
        int m = m0 + wm + mi * 16 + q * 4 + r;
        int b = m >> 8, s = m & 255;
        float v = acc[mi][ni][r] + bv;
        gx[(long)(((s << 2) | g) * 128 + b) * 1024 + hh] = (_Float16)v;
      }
    }
  }
}

// ---------------- banked barrier with detector+flag (the ONE change vs R2) ----------------
// Release fence (wbl2) before arrival; arrivals over 16 lines (cg&15); WG cg==0
// polls the 16-line sum, then RMWs the flag; others poll the flag. Acquire after.
__device__ __forceinline__ void gsync(unsigned int* grp, int cg, unsigned int epoch) {
  __syncthreads();  // drains each wave's vmem (h stores -> L2) before arrival
  if (threadIdx.x == 0) {
    __builtin_amdgcn_fence(__ATOMIC_RELEASE, "agent");  // wbl2: flush dirty L2 -> LLC
    __hip_atomic_fetch_add(grp + (cg & 15) * 32, 1u, __ATOMIC_RELAXED, __HIP_MEMORY_SCOPE_AGENT);
    unsigned int* flag = grp + 512;
    if (cg == 0) {
      const unsigned int target = epoch << 6;  // 64 * epoch
      for (;;) {
        unsigned int sum = 0;
#pragma unroll
        for (int i = 0; i < 16; i++)
          sum += __hip_atomic_load(grp + i * 32, __ATOMIC_RELAXED, __HIP_MEMORY_SCOPE_AGENT);
        if (sum >= target) break;
        __builtin_amdgcn_s_sleep(2);
      }
      __hip_atomic_fetch_add(flag, 1u, __ATOMIC_RELAXED, __HIP_MEMORY_SCOPE_AGENT);
    } else {
      while (__hip_atomic_load(flag, __ATOMIC_RELAXED, __HIP_MEMORY_SCOPE_AGENT) < epoch)
        __builtin_amdgcn_s_sleep(2);
    }
  }
  __syncthreads();
  __builtin_amdgcn_fence(__ATOMIC_ACQUIRE, "agent");  // buffer_inv: drop stale L1/L2
}

// ---------------- LSTM scan: EXACT R2 body, gsync swapped in ----------------
__global__ __launch_bounds__(256, 1) void k_lstm(const _Float16* __restrict__ gx, const _Float16* __restrict__ Wh,
                                                 _Float16* __restrict__ hbuf, float* __restrict__ hT,
                                                 unsigned int* __restrict__ bar) {
  __shared__ float pre[4][32][17];
  const int bid = blockIdx.x;
  const int cg = bid & 63, rs = bid >> 6;
  const int r0 = rs << 5, c0 = cg << 4;
  const int t = threadIdx.x, lane = t & 63, w = t >> 6;
  const int ln = lane & 15, q = lane >> 4;
  unsigned int* grp = bar + rs * 1024;  // 4 KB per group

  // pin this wave's W_h B-fragments: rows cg*64 + w*16 + ln, all K
  half8 breg[32];
  const _Float16* wrow = Wh + (cg * 64 + w * 16 + ln) * 1024 + q * 8;
#pragma unroll
  for (int ks = 0; ks < 32; ks++) breg[ks] = *(const half8*)(wrow + ks * 32);

  const int e0 = t << 1;
  const int erow = e0 >> 4, ecol = e0 & 15;
  *(unsigned int*)(hbuf + (r0 + erow) * 1024 + c0 + ecol) = 0u;

  float cst0 = 0.f, cst1 = 0.f;
  unsigned int ep = 1;
  gsync(grp, cg, ep); ep++;

  // prefetch gx for s=0 (R2's strided layout)
  float nx[2][4];
  {
    const _Float16* gp = gx + (long)((0 * 4 + w) * 128 + r0) * 1024 + c0 + ln;
#pragma unroll
    for (int mi = 0; mi < 2; mi++)
#pragma unroll
      for (int r = 0; r < 4; r++) nx[mi][r] = (float)gp[(mi * 16 + q * 4 + r) * 1024];
  }

  for (int s = 0; s < 256; s++) {
    const _Float16* hcur = hbuf + (s & 1) * 131072;
    _Float16* hnxt = hbuf + ((s + 1) & 1) * 131072;

    f32x4 acc0, acc1;
#pragma unroll
    for (int r = 0; r < 4; r++) { acc0[r] = nx[0][r]; acc1[r] = nx[1][r]; }

    // prefetch next step's gx (hidden under this step's K-loop)
    {
      int sp = (s < 255) ? s + 1 : 255;
      const _Float16* gp = gx + (long)((sp * 4 + w) * 128 + r0) * 1024 + c0 + ln;
#pragma unroll
      for (int mi = 0; mi < 2; mi++)
#pragma unroll
        for (int r = 0; r < 4; r++) nx[mi][r] = (float)gp[(mi * 16 + q * 4 + r) * 1024];
    }

    const _Float16* arow0 = hcur + (r0 + ln) * 1024 + q * 8;
    const _Float16* arow1 = arow0 + 16 * 1024;
#pragma unroll
    for (int ks = 0; ks < 32; ks++) {
      half8 a0 = *(const half8*)(arow0 + ks * 32);
      half8 a1 = *(const half8*)(arow1 + ks * 32);
      acc0 = MFMA16(a0, breg[ks], acc0);
      acc1 = MFMA16(a1, breg[ks], acc1);
    }

#pragma unroll
    for (int r = 0; r < 4; r++) {
      pre[w][q * 4 + r][ln] = acc0[r];
      pre[w][16 + q * 4 + r][ln] = acc1[r];
    }
    __syncthreads();

    float xi0 = pre[0][erow][ecol], xf0 = pre[1][erow][ecol];
    float xg0 = pre[2][erow][ecol], xo0 = pre[3][erow][ecol];
    float xi1 = pre[0][erow][ecol + 1], xf1 = pre[1][erow][ecol + 1];
    float xg1 = pre[2][erow][ecol + 1], xo1 = pre[3][erow][ecol + 1];
    float i0 = sigm(xi0), f0 = sigm(xf0), g0 = tanh_(xg0), o0 = sigm(xo0);
    float i1 = sigm(xi1), f1 = sigm(xf1), g1 = tanh_(xg1), o1 = sigm(xo1);
    cst0 = f0 * cst0 + i0 * g0;
    cst1 = f1 * cst1 + i1 * g1;
    float h0 = o0 * tanh_(cst0);
    float h1 = o1 * tanh_(cst1);
    union { _Float16 h[2]; unsigned int u; } pk;
    pk.h[0] = (_Float16)h0; pk.h[1] = (_Float16)h1;
    *(unsigned int*)(hnxt + (r0 + erow) * 1024 + c0 + ecol) = pk.u;
    if (s == 255) {
      float* hp = hT + (r0 + erow) * 1024 + c0 + ecol;
      hp[0] = h0; hp[1] = h1;
    } else {
      gsync(grp, cg, ep); ep++;
    }
  }
}

// ---------------- final FC (exact fp32) ----------------
__global__ __launch_bounds__(256) void k_fc(const float* __restrict__ hT, const float* __restrict__ W,
                                            const float* __restrict__ bias, float* __restrict__ out) {
  int gid = blockIdx.x * 4 + (threadIdx.x >> 6);  // wave id < 1280
  int lane = threadIdx.x & 63;
  int b = gid / 10, o = gid - b * 10;
  const float* hp = hT + b * 1024;
  const float* wp = W + o * 1024;
  float sum = 0.f;
  for (int k = lane; k < 1024; k += 64) sum += hp[k] * wp[k];
#pragma unroll
  for (int off = 32; off > 0; off >>= 1) sum += __shfl_down(sum, off, 64);
  if (lane == 0) out[b * 10 + o] = sum + bias[o];
}

// ---------------- launch ----------------
extern "C" void kernel_launch(void* const* d_in, const int* in_sizes, int n_in,
                              void* d_out, int out_size, void* d_ws, size_t ws_size,
                              hipStream_t stream) {
  const int* x = (const int*)d_in[0];
  const float* emb = (const float*)d_in[1];
  const float* Wii = (const float*)d_in[2];
  const float* bii = (const float*)d_in[3];
  const float* Whi = (const float*)d_in[4];
  const float* Wif = (const float*)d_in[5];
  const float* bif = (const float*)d_in[6];
  const float* Whf = (const float*)d_in[7];
  const float* Wig = (const float*)d_in[8];
  const float* big = (const float*)d_in[9];
  const float* Whg = (const float*)d_in[10];
  const float* Wio = (const float*)d_in[11];
  const float* bio = (const float*)d_in[12];
  const float* Who = (const float*)d_in[13];
  const float* fcW = (const float*)d_in[14];
  const float* fcb = (const float*)d_in[15];

  char* ws = (char*)d_ws;
  _Float16* gx = (_Float16*)ws;                    // 268,435,456 B
  _Float16* E = (_Float16*)(ws + 268435456);       // 33,554,432 B
  _Float16* WiB = (_Float16*)(ws + 301989888);     // 4,194,304 B
  _Float16* WhB = (_Float16*)(ws + 306184192);     // 8,388,608 B
  float* biasC = (float*)(ws + 314572800);         // 16,384 B
  _Float16* hbuf = (_Float16*)(ws + 314589184);    // 524,288 B
  float* hT = (float*)(ws + 315113472);            // 524,288 B
  unsigned int* bar = (unsigned int*)(ws + 315637760);  // 16,384 B (total ~316 MB)
  float* out = (float*)d_out;

  k_cast_e<<<8192, 256, 0, stream>>>(x, emb, E);
  k_cast_wi<<<1024, 256, 0, stream>>>(Wii, Wif, Wig, Wio, WiB);
  k_cast_wh<<<2048, 256, 0, stream>>>(Whi, Whf, Whg, Who, WhB);
  k_cast_bias<<<16, 256, 0, stream>>>(bii, bif, big, bio, biasC);
  k_gemm1<<<8192, 256, 0, stream>>>(E, WiB, biasC, gx);
  k_zero<<<16, 256, 0, stream>>>(bar);

  const _Float16* gx_a = gx;
  const _Float16* wh_a = WhB;
  _Float16* hb_a = hbuf;
  float* ht_a = hT;
  unsigned int* bar_a = bar;
  void* kargs[] = {(void*)&gx_a, (void*)&wh_a, (void*)&hb_a, (void*)&ht_a, (void*)&bar_a};
  hipLaunchCooperativeKernel(k_lstm, dim3(256), dim3(256), kargs, 0, stream);

  k_fc<<<320, 256, 0, stream>>>(hT, fcW, fcb, out);
}

// Round 6
// 4973.047 us; speedup vs baseline: 1.9284x; 1.2322x over previous
//
#include <hip/hip_runtime.h>
#include <hip/hip_cooperative_groups.h>

// Problem: B=128, S=256, V=50000, E=512, H=1024, O=10
// R6 = R5 with ONE mechanism change: no agent fences. h is exchanged through
// the LLC via device(agent)-scope relaxed atomic stores/loads (sc1 path that
// bypasses the non-coherent per-XCD L2). Barrier = banked arrivals + detector
// + flag (R5-proven), minus the release/acquire fences. gx/Wh stay plain
// loads and now persist in L2 across steps (no per-step invalidate).

typedef __attribute__((ext_vector_type(8))) _Float16 half8;
typedef __attribute__((ext_vector_type(4))) float f32x4;

#define MFMA16(a, b, c) __builtin_amdgcn_mfma_f32_16x16x32_f16((a), (b), (c), 0, 0, 0)

__device__ __forceinline__ float sigm(float x) { return 1.0f / (1.0f + __expf(-x)); }
__device__ __forceinline__ float tanh_(float x) { return 1.0f - 2.0f / (__expf(2.0f * x) + 1.0f); }

// ---------------- cast / gather kernels ----------------

__global__ __launch_bounds__(256) void k_cast_e(const int* __restrict__ x,
                                                const float* __restrict__ emb,
                                                _Float16* __restrict__ e) {
  int idx = (blockIdx.x * 256 + threadIdx.x) * 8;  // < 16777216
  int m = idx >> 9, k = idx & 511;
  int tok = x[m];
  const float* src = emb + (long)tok * 512 + k;
  float4 a = *(const float4*)src;
  float4 b = *(const float4*)(src + 4);
  half8 h;
  h[0] = (_Float16)a.x; h[1] = (_Float16)a.y; h[2] = (_Float16)a.z; h[3] = (_Float16)a.w;
  h[4] = (_Float16)b.x; h[5] = (_Float16)b.y; h[6] = (_Float16)b.z; h[7] = (_Float16)b.w;
  *(half8*)(e + idx) = h;
}

__global__ __launch_bounds__(256) void k_cast_wi(const float* __restrict__ Wii, const float* __restrict__ Wif,
                                                 const float* __restrict__ Wig, const float* __restrict__ Wio,
                                                 _Float16* __restrict__ Wi) {
  int idx = (blockIdx.x * 256 + threadIdx.x) * 8;  // < 2097152
  int g = idx >> 19;
  const float* src = (g == 0) ? Wii : (g == 1) ? Wif : (g == 2) ? Wig : Wio;
  src += idx & 524287;
  float4 a = *(const float4*)src;
  float4 b = *(const float4*)(src + 4);
  half8 h;
  h[0] = (_Float16)a.x; h[1] = (_Float16)a.y; h[2] = (_Float16)a.z; h[3] = (_Float16)a.w;
  h[4] = (_Float16)b.x; h[5] = (_Float16)b.y; h[6] = (_Float16)b.z; h[7] = (_Float16)b.w;
  *(half8*)(Wi + idx) = h;
}

// Wh_f16[n'][k], n' = cg*64 + g*16 + cc  (h-col = cg*16+cc), k<1024
__global__ __launch_bounds__(256) void k_cast_wh(const float* __restrict__ Whi, const float* __restrict__ Whf,
                                                 const float* __restrict__ Whg, const float* __restrict__ Who,
                                                 _Float16* __restrict__ Wh) {
  int idx = (blockIdx.x * 256 + threadIdx.x) * 8;  // < 4194304
  int n = idx >> 10, k = idx & 1023;
  int cg = n >> 6, rem = n & 63, g = rem >> 4, cc = rem & 15;
  const float* src = (g == 0) ? Whi : (g == 1) ? Whf : (g == 2) ? Whg : Who;
  src += (cg * 16 + cc) * 1024 + k;
  float4 a = *(const float4*)src;
  float4 b = *(const float4*)(src + 4);
  half8 h;
  h[0] = (_Float16)a.x; h[1] = (_Float16)a.y; h[2] = (_Float16)a.z; h[3] = (_Float16)a.w;
  h[4] = (_Float16)b.x; h[5] = (_Float16)b.y; h[6] = (_Float16)b.z; h[7] = (_Float16)b.w;
  *(half8*)(Wh + idx) = h;
}

__global__ __launch_bounds__(256) void k_cast_bias(const float* __restrict__ bii, const float* __restrict__ bif,
                                                   const float* __restrict__ big, const float* __restrict__ bio,
                                                   float* __restrict__ bc) {
  int n = blockIdx.x * 256 + threadIdx.x;  // < 4096
  int g = n >> 10, hh = n & 1023;
  const float* src = (g == 0) ? bii : (g == 1) ? bif : (g == 2) ? big : bio;
  bc[n] = src[hh];
}

__global__ void k_zero(unsigned int* p) { p[blockIdx.x * 256 + threadIdx.x] = 0u; }

// ---------------- GEMM1: gx[s][g][b][h] = e @ Wi^T + bias (R2/R5-proven) ----------------
__global__ __launch_bounds__(256) void k_gemm1(const _Float16* __restrict__ E, const _Float16* __restrict__ Wi,
                                               const float* __restrict__ bias, _Float16* __restrict__ gx) {
  __shared__ _Float16 As[128][40];
  __shared__ _Float16 Bs[128][40];
  const int t = threadIdx.x;
  const int bm = blockIdx.x >> 5, bn = blockIdx.x & 31;
  const int m0 = bm << 7, n0 = bn << 7;
  const int lane = t & 63, wv = t >> 6;
  const int wm = (wv >> 1) << 6, wn = (wv & 1) << 6;
  const int ln = lane & 15, q = lane >> 4;
  const int rowA0 = t >> 2, kc0 = t & 3;
  const int rowA1 = (t + 256) >> 2, kc1 = (t + 256) & 3;

  f32x4 acc[4][4] = {};

  for (int k0 = 0; k0 < 512; k0 += 32) {
    *(half8*)&As[rowA0][kc0 * 8] = *(const half8*)(E + (m0 + rowA0) * 512 + k0 + kc0 * 8);
    *(half8*)&As[rowA1][kc1 * 8] = *(const half8*)(E + (m0 + rowA1) * 512 + k0 + kc1 * 8);
    *(half8*)&Bs[rowA0][kc0 * 8] = *(const half8*)(Wi + (n0 + rowA0) * 512 + k0 + kc0 * 8);
    *(half8*)&Bs[rowA1][kc1 * 8] = *(const half8*)(Wi + (n0 + rowA1) * 512 + k0 + kc1 * 8);
    __syncthreads();
    half8 af[4], bf[4];
#pragma unroll
    for (int i = 0; i < 4; i++) af[i] = *(const half8*)&As[wm + i * 16 + ln][q * 8];
#pragma unroll
    for (int i = 0; i < 4; i++) bf[i] = *(const half8*)&Bs[wn + i * 16 + ln][q * 8];
#pragma unroll
    for (int mi = 0; mi < 4; mi++)
#pragma unroll
      for (int ni = 0; ni < 4; ni++) acc[mi][ni] = MFMA16(af[mi], bf[ni], acc[mi][ni]);
    __syncthreads();
  }

#pragma unroll
  for (int ni = 0; ni < 4; ni++) {
    int n = n0 + wn + ni * 16 + ln;
    float bv = bias[n];
    int g = n >> 10, hh = n & 1023;
#pragma unroll
    for (int mi = 0; mi < 4; mi++) {
#pragma unroll
      for (int r = 0; r < 4; r++) {
        int m = m0 + wm + mi * 16 + q * 4 + r;
        int b = m >> 8, s = m & 255;
        float v = acc[mi][ni][r] + bv;
        gx[(long)(((s << 2) | g) * 128 + b) * 1024 + hh] = (_Float16)v;
      }
    }
  }
}

// ---------------- fence-free banked barrier (per 64-WG group) ----------------
// h traffic is all sc1 (LLC-coherent), so no wbl2/inv needed. __syncthreads()
// drains each wave's vmcnt -> h stores are LLC-visible before the arrival RMW.
__device__ __forceinline__ void gsync(unsigned int* grp, int cg, unsigned int epoch) {
  __syncthreads();  // emits s_waitcnt vmcnt(0) before s_barrier: h stores acked
  if (threadIdx.x == 0) {
    __hip_atomic_fetch_add(grp + (cg & 15) * 32, 1u, __ATOMIC_RELAXED, __HIP_MEMORY_SCOPE_AGENT);
    unsigned int* flag = grp + 512;
    if (cg == 0) {
      const unsigned int target = epoch << 6;  // 64 * epoch
      for (;;) {
        unsigned int sum = 0;
#pragma unroll
        for (int i = 0; i < 16; i++)
          sum += __hip_atomic_load(grp + i * 32, __ATOMIC_RELAXED, __HIP_MEMORY_SCOPE_AGENT);
        if (sum >= target) break;
        __builtin_amdgcn_s_sleep(2);
      }
      __hip_atomic_fetch_add(flag, 1u, __ATOMIC_RELAXED, __HIP_MEMORY_SCOPE_AGENT);
    } else {
      while (__hip_atomic_load(flag, __ATOMIC_RELAXED, __HIP_MEMORY_SCOPE_AGENT) < epoch)
        __builtin_amdgcn_s_sleep(2);
    }
  }
  __syncthreads();
}

// ---------------- LSTM scan: R5 body, h exchange via agent-scope atomics ----------------
__global__ __launch_bounds__(256, 1) void k_lstm(const _Float16* __restrict__ gx, const _Float16* __restrict__ Wh,
                                                 _Float16* __restrict__ hbuf, float* __restrict__ hT,
                                                 unsigned int* __restrict__ bar) {
  __shared__ float pre[4][32][17];
  const int bid = blockIdx.x;
  const int cg = bid & 63, rs = bid >> 6;
  const int r0 = rs << 5, c0 = cg << 4;
  const int t = threadIdx.x, lane = t & 63, w = t >> 6;
  const int ln = lane & 15, q = lane >> 4;
  unsigned int* grp = bar + rs * 1024;  // 4 KB per group

  // this wave's W_h B-fragments: rows cg*64 + w*16 + ln, all K (plain loads; L2-resident)
  half8 breg[32];
  const _Float16* wrow = Wh + (cg * 64 + w * 16 + ln) * 1024 + q * 8;
#pragma unroll
  for (int ks = 0; ks < 32; ks++) breg[ks] = *(const half8*)(wrow + ks * 32);

  const int e0 = t << 1;
  const int erow = e0 >> 4, ecol = e0 & 15;
  // zero our slice of h buffer 0 (sc1 write-through: LLC-visible to all XCDs)
  __hip_atomic_store((unsigned int*)(hbuf + (r0 + erow) * 1024 + c0 + ecol), 0u,
                     __ATOMIC_RELAXED, __HIP_MEMORY_SCOPE_AGENT);

  float cst0 = 0.f, cst1 = 0.f;
  unsigned int ep = 1;
  gsync(grp, cg, ep); ep++;

  // prefetch gx for s=0 (plain loads; L2-cacheable)
  float nx[2][4];
  {
    const _Float16* gp = gx + (long)((0 * 4 + w) * 128 + r0) * 1024 + c0 + ln;
#pragma unroll
    for (int mi = 0; mi < 2; mi++)
#pragma unroll
      for (int r = 0; r < 4; r++) nx[mi][r] = (float)gp[(mi * 16 + q * 4 + r) * 1024];
  }

  for (int s = 0; s < 256; s++) {
    const _Float16* hcur = hbuf + (s & 1) * 131072;
    _Float16* hnxt = hbuf + ((s + 1) & 1) * 131072;

    f32x4 acc0, acc1;
#pragma unroll
    for (int r = 0; r < 4; r++) { acc0[r] = nx[0][r]; acc1[r] = nx[1][r]; }

    // prefetch next step's gx (hidden under this step's K-loop)
    {
      int sp = (s < 255) ? s + 1 : 255;
      const _Float16* gp = gx + (long)((sp * 4 + w) * 128 + r0) * 1024 + c0 + ln;
#pragma unroll
      for (int mi = 0; mi < 2; mi++)
#pragma unroll
        for (int r = 0; r < 4; r++) nx[mi][r] = (float)gp[(mi * 16 + q * 4 + r) * 1024];
    }

    // K-loop: h fragments via agent-scope relaxed atomic u64 loads (sc1: LLC-coherent)
    const unsigned long long* arow0 = (const unsigned long long*)(hcur + (r0 + ln) * 1024 + q * 8);
    const unsigned long long* arow1 = arow0 + 16 * 256;  // +16 rows (1024 fp16 = 256 u64 per row)
#pragma unroll
    for (int ks = 0; ks < 32; ks++) {
      union { unsigned long long q[2]; half8 v; } a0u, a1u;
      a0u.q[0] = __hip_atomic_load(arow0 + ks * 8, __ATOMIC_RELAXED, __HIP_MEMORY_SCOPE_AGENT);
      a0u.q[1] = __hip_atomic_load(arow0 + ks * 8 + 1, __ATOMIC_RELAXED, __HIP_MEMORY_SCOPE_AGENT);
      a1u.q[0] = __hip_atomic_load(arow1 + ks * 8, __ATOMIC_RELAXED, __HIP_MEMORY_SCOPE_AGENT);
      a1u.q[1] = __hip_atomic_load(arow1 + ks * 8 + 1, __ATOMIC_RELAXED, __HIP_MEMORY_SCOPE_AGENT);
      acc0 = MFMA16(a0u.v, breg[ks], acc0);
      acc1 = MFMA16(a1u.v, breg[ks], acc1);
    }

#pragma unroll
    for (int r = 0; r < 4; r++) {
      pre[w][q * 4 + r][ln] = acc0[r];
      pre[w][16 + q * 4 + r][ln] = acc1[r];
    }
    __syncthreads();

    float xi0 = pre[0][erow][ecol], xf0 = pre[1][erow][ecol];
    float xg0 = pre[2][erow][ecol], xo0 = pre[3][erow][ecol];
    float xi1 = pre[0][erow][ecol + 1], xf1 = pre[1][erow][ecol + 1];
    float xg1 = pre[2][erow][ecol + 1], xo1 = pre[3][erow][ecol + 1];
    float i0 = sigm(xi0), f0 = sigm(xf0), g0 = tanh_(xg0), o0 = sigm(xo0);
    float i1 = sigm(xi1), f1 = sigm(xf1), g1 = tanh_(xg1), o1 = sigm(xo1);
    cst0 = f0 * cst0 + i0 * g0;
    cst1 = f1 * cst1 + i1 * g1;
    float h0 = o0 * tanh_(cst0);
    float h1 = o1 * tanh_(cst1);
    union { _Float16 h[2]; unsigned int u; } pk;
    pk.h[0] = (_Float16)h0; pk.h[1] = (_Float16)h1;
    // sc1 write-through store: LLC-visible, no fence needed
    __hip_atomic_store((unsigned int*)(hnxt + (r0 + erow) * 1024 + c0 + ecol), pk.u,
                       __ATOMIC_RELAXED, __HIP_MEMORY_SCOPE_AGENT);
    if (s == 255) {
      float* hp = hT + (r0 + erow) * 1024 + c0 + ecol;
      hp[0] = h0; hp[1] = h1;
    } else {
      gsync(grp, cg, ep); ep++;
    }
  }
}

// ---------------- final FC (exact fp32) ----------------
__global__ __launch_bounds__(256) void k_fc(const float* __restrict__ hT, const float* __restrict__ W,
                                            const float* __restrict__ bias, float* __restrict__ out) {
  int gid = blockIdx.x * 4 + (threadIdx.x >> 6);  // wave id < 1280
  int lane = threadIdx.x & 63;
  int b = gid / 10, o = gid - b * 10;
  const float* hp = hT + b * 1024;
  const float* wp = W + o * 1024;
  float sum = 0.f;
  for (int k = lane; k < 1024; k += 64) sum += hp[k] * wp[k];
#pragma unroll
  for (int off = 32; off > 0; off >>= 1) sum += __shfl_down(sum, off, 64);
  if (lane == 0) out[b * 10 + o] = sum + bias[o];
}

// ---------------- launch ----------------
extern "C" void kernel_launch(void* const* d_in, const int* in_sizes, int n_in,
                              void* d_out, int out_size, void* d_ws, size_t ws_size,
                              hipStream_t stream) {
  const int* x = (const int*)d_in[0];
  const float* emb = (const float*)d_in[1];
  const float* Wii = (const float*)d_in[2];
  const float* bii = (const float*)d_in[3];
  const float* Whi = (const float*)d_in[4];
  const float* Wif = (const float*)d_in[5];
  const float* bif = (const float*)d_in[6];
  const float* Whf = (const float*)d_in[7];
  const float* Wig = (const float*)d_in[8];
  const float* big = (const float*)d_in[9];
  const float* Whg = (const float*)d_in[10];
  const float* Wio = (const float*)d_in[11];
  const float* bio = (const float*)d_in[12];
  const float* Who = (const float*)d_in[13];
  const float* fcW = (const float*)d_in[14];
  const float* fcb = (const float*)d_in[15];

  char* ws = (char*)d_ws;
  _Float16* gx = (_Float16*)ws;                    // 268,435,456 B
  _Float16* E = (_Float16*)(ws + 268435456);       // 33,554,432 B
  _Float16* WiB = (_Float16*)(ws + 301989888);     // 4,194,304 B
  _Float16* WhB = (_Float16*)(ws + 306184192);     // 8,388,608 B
  float* biasC = (float*)(ws + 314572800);         // 16,384 B
  _Float16* hbuf = (_Float16*)(ws + 314589184);    // 524,288 B
  float* hT = (float*)(ws + 315113472);            // 524,288 B
  unsigned int* bar = (unsigned int*)(ws + 315637760);  // 16,384 B (total ~316 MB)
  float* out = (float*)d_out;

  k_cast_e<<<8192, 256, 0, stream>>>(x, emb, E);
  k_cast_wi<<<1024, 256, 0, stream>>>(Wii, Wif, Wig, Wio, WiB);
  k_cast_wh<<<2048, 256, 0, stream>>>(Whi, Whf, Whg, Who, WhB);
  k_cast_bias<<<16, 256, 0, stream>>>(bii, bif, big, bio, biasC);
  k_gemm1<<<8192, 256, 0, stream>>>(E, WiB, biasC, gx);
  k_zero<<<16, 256, 0, stream>>>(bar);

  const _Float16* gx_a = gx;
  const _Float16* wh_a = WhB;
  _Float16* hb_a = hbuf;
  float* ht_a = hT;
  unsigned int* bar_a = bar;
  void* kargs[] = {(void*)&gx_a, (void*)&wh_a, (void*)&hb_a, (void*)&ht_a, (void*)&bar_a};
  hipLaunchCooperativeKernel(k_lstm, dim3(256), dim3(256), kargs, 0, stream);

  k_fc<<<320, 256, 0, stream>>>(hT, fcW, fcb, out);
}